// Round 5
// baseline (150.721 us; speedup 1.0000x reference)
//
#include <hip/hip_runtime.h>

// ContextVector additive-attention (Bahdanau) — round 5.
// R5 vs R4: (1) phase-1 reciprocal via bit-trick seed + 2 packed-Newton steps
// (no v_rcp in the hot loop: 12 cyc/pair vs 32); (2) prep GEMMs rewritten as
// LDS-staged tiles with 1536 blocks (R4's uniform-load version was latency-
// bound at ~40us); (3) attn LDS cut to ~25KB + launch_bounds(512,8) for
// full occupancy.

constexpr int B  = 8;
constexpr int TE = 512;   // T_enc
constexpr int DE = 256;   // D_enc
constexpr int TD = 256;   // T_dec
constexpr int DD = 512;   // D_dec

constexpr float LOG2E  = 1.4426950408889634f;
constexpr float K2     = 2.8853900817779268f;   // 2*log2(e)
constexpr float TCLAMP = 0.99999988f;           // < 1 so 1+ta*tb stays > 0
constexpr unsigned RCP_MAGIC = 0x7EF311C3u;     // seed: ~4.9% max rel err

typedef float f2 __attribute__((ext_vector_type(2)));

__device__ __forceinline__ float fexp2(float x){ return __builtin_amdgcn_exp2f(x); }
__device__ __forceinline__ float frcp (float x){ return __builtin_amdgcn_rcpf(x); }
__device__ __forceinline__ f2 pk_add(f2 a, f2 b){ f2 d; asm("v_pk_add_f32 %0, %1, %2":"=v"(d):"v"(a),"v"(b)); return d; }
__device__ __forceinline__ f2 pk_mul(f2 a, f2 b){ f2 d; asm("v_pk_mul_f32 %0, %1, %2":"=v"(d):"v"(a),"v"(b)); return d; }
__device__ __forceinline__ f2 pk_fma(f2 a, f2 b, f2 c){ f2 d; asm("v_pk_fma_f32 %0, %1, %2, %3":"=v"(d):"v"(a),"v"(b),"v"(c)); return d; }

__device__ __forceinline__ float tanh_fast(float z){
  const float E = fexp2(K2*z);                 // e^{2z}
  const float t = 1.f - 2.f*frcp(1.f + E);
  return fminf(fmaxf(t, -TCLAMP), TCLAMP);
}

// 1/d for d in (0,2]: bit-trick seed + 2 Newton steps, all pk-math.
// dpos = d, dneg = -d. Rel err ~6e-6.
__device__ __forceinline__ f2 rcp_nr2(f2 dpos, f2 dneg, f2 two2){
  f2 x0;
  x0.x = __int_as_float((int)(RCP_MAGIC - (unsigned)__float_as_int(dpos.x)));
  x0.y = __int_as_float((int)(RCP_MAGIC - (unsigned)__float_as_int(dpos.y)));
  const f2 t1 = pk_fma(dneg, x0, two2);   // 2 - d*x0
  const f2 x1 = pk_mul(x0, t1);
  const f2 t2 = pk_fma(dneg, x1, two2);
  return pk_mul(x1, t2);
}

// Prep: blocks [0,1024): encT[b][e][t] = tanh(encW) (transposed store)
//       blocks [1024,1536): decT[b*TD+s][e] = tanh(decW) (row-major)
// LDS-staged W tile (4 cols), uniform b128 broadcast reads, 16 FMA / 4 ds.
__global__ __launch_bounds__(256, 8)
void prep_kernel(const float* __restrict__ enc, const float* __restrict__ Wenc,
                 const float* __restrict__ dec, const float* __restrict__ Wdec,
                 float* __restrict__ encT, float* __restrict__ decT)
{
  __shared__ __align__(16) float Ws[512*4];   // [k][4 cols], 8 KB
  const int tid = threadIdx.x;
  const int bid = blockIdx.x;
  if (bid < 1024){
    const int rg = bid >> 6, eg = bid & 63, e0 = eg*4;
    *(float4*)&Ws[tid*4] = *(const float4*)(Wenc + (size_t)tid*DE + e0);
    __syncthreads();
    const int row = rg*256 + tid;          // b*TE + t
    const int b = row >> 9, t = row & (TE-1);
    const float* rp = enc + (size_t)row*DE;
    float a0=0.f,a1=0.f,a2=0.f,a3=0.f;
    #pragma unroll 4
    for (int k4=0;k4<DE/4;k4++){
      const float4 a = *(const float4*)(rp + 4*k4);
      const float aj[4] = {a.x,a.y,a.z,a.w};
      #pragma unroll
      for (int j=0;j<4;j++){
        const float4 w = *(const float4*)&Ws[(4*k4+j)*4];   // uniform b128
        a0 += aj[j]*w.x; a1 += aj[j]*w.y; a2 += aj[j]*w.z; a3 += aj[j]*w.w;
      }
    }
    float* op = encT + (size_t)(b*DE + e0)*TE + t;   // coalesced over t
    op[0*TE] = tanh_fast(a0); op[1*TE] = tanh_fast(a1);
    op[2*TE] = tanh_fast(a2); op[3*TE] = tanh_fast(a3);
  } else {
    const int bid2 = bid - 1024;
    const int rg = bid2 >> 6, eg = bid2 & 63, e0 = eg*4;
    *(float4*)&Ws[tid*4]       = *(const float4*)(Wdec + (size_t)tid*DE + e0);
    *(float4*)&Ws[(tid+256)*4] = *(const float4*)(Wdec + (size_t)(tid+256)*DE + e0);
    __syncthreads();
    const int row = rg*256 + tid;          // b*TD + s
    const float* rp = dec + (size_t)row*DD;
    float a0=0.f,a1=0.f,a2=0.f,a3=0.f;
    #pragma unroll 4
    for (int k4=0;k4<DD/4;k4++){
      const float4 a = *(const float4*)(rp + 4*k4);
      const float aj[4] = {a.x,a.y,a.z,a.w};
      #pragma unroll
      for (int j=0;j<4;j++){
        const float4 w = *(const float4*)&Ws[(4*k4+j)*4];   // uniform b128
        a0 += aj[j]*w.x; a1 += aj[j]*w.y; a2 += aj[j]*w.z; a3 += aj[j]*w.w;
      }
    }
    float4 o; o.x=tanh_fast(a0); o.y=tanh_fast(a1); o.z=tanh_fast(a2); o.w=tanh_fast(a3);
    *(float4*)(decT + (size_t)row*DE + e0) = o;
  }
}

// Main kernel: block = (b, 4 decoder steps). 512 blocks x 512 threads.
// phase1: logit[s][t] = sum_e vv_e*(ta+tb)/(1+ta*tb), via Newton-rcp (no trans)
// phase2: softmax over t (log2 domain)
// phase3: context = weights @ enc
template<bool USE_DWT>
__global__ __launch_bounds__(512, 8)
void attn_kernel(const float* __restrict__ enc, const float* __restrict__ dec,
                 const float* __restrict__ Wdec, const float* __restrict__ v,
                 const float* __restrict__ encT, const float* __restrict__ decT,
                 float* __restrict__ outCtx, float* __restrict__ outW)
{
  __shared__ __align__(16) float tw4[DE*4];    // 4 KB  {tb_s0..s3} per e
  __shared__ __align__(16) float vtb4[DE*4];   // 4 KB  {vv*tb} per e
  __shared__ float vv[DE];                     // 1 KB  LOG2E * v
  __shared__ __align__(16) float part[2*4*TE]; // 16 KB multi-use
  __shared__ float wred[8], wsum2[8], rs[4];

  const int tid = threadIdx.x;
  const int b  = blockIdx.x >> 6;
  const int s0 = (blockIdx.x & 63)*4;

  if (USE_DWT){
    if (tid < DE){
      const float* dp = decT + (size_t)(b*TD + s0)*DE + tid;
      float4 t4; t4.x = dp[0]; t4.y = dp[DE]; t4.z = dp[2*DE]; t4.w = dp[3*DE];
      const float ve = LOG2E * v[tid];
      *(float4*)&tw4[tid*4] = t4;
      float4 vt; vt.x=ve*t4.x; vt.y=ve*t4.y; vt.z=ve*t4.z; vt.w=ve*t4.w;
      *(float4*)&vtb4[tid*4] = vt;
      vv[tid] = ve;
    }
    __syncthreads();
  } else {
    {
      float* Ds = part;                              // reuse 8 KB of part
      const float* src = dec + (size_t)(b*TD + s0)*DD;
      #pragma unroll
      for (int i=0;i<4;i++) Ds[tid + i*512] = src[tid + i*512];
      if (tid < DE) vv[tid] = LOG2E * v[tid];
    }
    __syncthreads();
    const int h = tid >> 8, e = tid & 255;
    float a0=0.f, a1=0.f;
    const float* wp  = Wdec + e;
    const float* d0p = part + (2*h  )*DD;
    const float* d1p = part + (2*h+1)*DD;
    #pragma unroll 2
    for (int k4=0;k4<DD/4;k4++){
      const float4 qa = *(const float4*)(d0p + 4*k4);
      const float4 qb = *(const float4*)(d1p + 4*k4);
      const float w0 = wp[(size_t)(4*k4  )*DE];
      const float w1 = wp[(size_t)(4*k4+1)*DE];
      const float w2 = wp[(size_t)(4*k4+2)*DE];
      const float w3 = wp[(size_t)(4*k4+3)*DE];
      a0 += qa.x*w0+qa.y*w1+qa.z*w2+qa.w*w3;
      a1 += qb.x*w0+qb.y*w1+qb.z*w2+qb.w*w3;
    }
    const float t0v = tanh_fast(a0), t1v = tanh_fast(a1);
    const float ve = vv[e];
    *(f2*)&tw4[e*4 + 2*h]  = f2{t0v, t1v};
    *(f2*)&vtb4[e*4 + 2*h] = f2{ve*t0v, ve*t1v};
    __syncthreads();
  }

  // ---- phase 1: thread (g = e-half, q = t-pair). acc[s] over 2 t. ----
  {
    const int g = tid >> 8, q = tid & 255;
    f2 acc[4];
    #pragma unroll
    for (int s=0;s<4;s++) acc[s] = f2{0.f, 0.f};
    const f2 one2 = {1.f,1.f}, mone2 = {-1.f,-1.f}, two2 = {2.f,2.f};
    const float* xp  = encT + (size_t)(b*DE + 128*g)*TE + 2*q;
    const float* twp = tw4  + 128*g*4;
    const float* vbp = vtb4 + 128*g*4;
    const float* vvp = vv   + 128*g;
    #pragma unroll 4
    for (int i=0;i<128;i++){
      const f2 ta = *(const f2*)(xp + (size_t)i*TE);   // coalesced b64
      const float4 tb = *(const float4*)(twp + i*4);   // uniform b128
      const float4 vb = *(const float4*)(vbp + i*4);   // uniform b128
      const float ve = vvp[i];                         // uniform b32
      const f2 veta = pk_mul(f2{ve,ve}, ta);
      const float tbc[4] = {tb.x,tb.y,tb.z,tb.w};
      const float vbc[4] = {vb.x,vb.y,vb.z,vb.w};
      #pragma unroll
      for (int s=0;s<4;s++){
        const f2 tbs = {tbc[s], tbc[s]};
        const f2 u    = pk_mul(ta, tbs);
        const f2 dpos = pk_add(one2, u);
        const f2 dneg = pk_fma(u, mone2, mone2);       // -(1+u)
        const f2 r    = rcp_nr2(dpos, dneg, two2);
        const f2 num  = pk_add(veta, f2{vbc[s], vbc[s]});
        acc[s] = pk_fma(num, r, acc[s]);
      }
    }
    #pragma unroll
    for (int s=0;s<4;s++)
      *(f2*)&part[(g*4 + s)*TE + 2*q] = acc[s];
  }
  __syncthreads();

  // ---- phase 2: softmax. wave w: s = w>>1, half c = w&1 (256 t each). ----
  {
    const int w = tid >> 6, lane = tid & 63;
    const int s = w >> 1, c = w & 1;
    const int t0 = c*256 + 4*lane;
    const float4 p0 = *(const float4*)&part[(0*4 + s)*TE + t0];
    const float4 p1 = *(const float4*)&part[(1*4 + s)*TE + t0];
    float4 al;
    al.x = p0.x+p1.x; al.y = p0.y+p1.y; al.z = p0.z+p1.z; al.w = p0.w+p1.w;
    float m = fmaxf(fmaxf(al.x,al.y), fmaxf(al.z,al.w));
    #pragma unroll
    for (int off=32; off>=1; off>>=1) m = fmaxf(m, __shfl_xor(m, off));
    if (lane==0) wred[w] = m;
    __syncthreads();
    const float M = fmaxf(wred[2*s], wred[2*s+1]);
    float4 ex;
    ex.x = fexp2(al.x - M); ex.y = fexp2(al.y - M);
    ex.z = fexp2(al.z - M); ex.w = fexp2(al.w - M);
    float sum = ex.x+ex.y+ex.z+ex.w;
    #pragma unroll
    for (int off=32; off>=1; off>>=1) sum += __shfl_xor(sum, off);
    if (lane==0) wsum2[w] = sum;
    __syncthreads();
    const float S = wsum2[2*s] + wsum2[2*s+1];
    const float r = 1.0f / S;
    float4 wo; wo.x=ex.x*r; wo.y=ex.y*r; wo.z=ex.z*r; wo.w=ex.w*r;
    *(float4*)(outW + (size_t)(b*TD + s0 + s)*TE + t0) = wo;
    *(float4*)&part[(0*4 + s)*TE + t0] = ex;   // own slot: race-free
    if (lane==0 && c==0) rs[s] = r;
  }
  __syncthreads();

  // ---- phase 3: context. thread (h = t-half, e). ----
  {
    const int h = tid >> 8, e = tid & 255;
    float c0=0.f, c1=0.f, c2=0.f, c3=0.f;
    const float* encB = enc + (size_t)(b*TE + 256*h)*DE + e;
    const float* pb = part + 256*h;           // part[(0,s)][t] rows, stride TE
    #pragma unroll 2
    for (int t4=0;t4<64;t4++){
      const float4 q0 = *(const float4*)(pb + 0*TE + 4*t4);   // uniform b128
      const float4 q1 = *(const float4*)(pb + 1*TE + 4*t4);
      const float4 q2 = *(const float4*)(pb + 2*TE + 4*t4);
      const float4 q3 = *(const float4*)(pb + 3*TE + 4*t4);
      const float f0 = encB[(size_t)(4*t4  )*DE];
      const float f1 = encB[(size_t)(4*t4+1)*DE];
      const float f2_ = encB[(size_t)(4*t4+2)*DE];
      const float f3 = encB[(size_t)(4*t4+3)*DE];
      c0 += q0.x*f0+q0.y*f1+q0.z*f2_+q0.w*f3;
      c1 += q1.x*f0+q1.y*f1+q1.z*f2_+q1.w*f3;
      c2 += q2.x*f0+q2.y*f1+q2.z*f2_+q2.w*f3;
      c3 += q3.x*f0+q3.y*f1+q3.z*f2_+q3.w*f3;
    }
    float* partc = part + 4*TE;               // part[1] region: 8 KB
    partc[(h*4+0)*DE + e] = c0;
    partc[(h*4+1)*DE + e] = c1;
    partc[(h*4+2)*DE + e] = c2;
    partc[(h*4+3)*DE + e] = c3;
  }
  __syncthreads();
  if (tid < DE){
    const float* partc = part + 4*TE;
    #pragma unroll
    for (int s=0;s<4;s++){
      const float val = (partc[s*DE + tid] + partc[(4+s)*DE + tid]) * rs[s];
      outCtx[(size_t)(b*TD + s0 + s)*DE + tid] = val;
    }
  }
}

extern "C" void kernel_launch(void* const* d_in, const int* in_sizes, int n_in,
                              void* d_out, int out_size, void* d_ws, size_t ws_size,
                              hipStream_t stream)
{
  const float* enc  = (const float*)d_in[0];
  const float* dec  = (const float*)d_in[1];
  const float* Wenc = (const float*)d_in[2];
  const float* Wdec = (const float*)d_in[3];
  const float* v    = (const float*)d_in[4];
  float* outCtx = (float*)d_out;                       // (8,256,256)
  float* outW   = outCtx + (size_t)B*TD*DE;            // (8,256,512)
  float* encT   = (float*)d_ws;                        // 4 MB
  float* decT   = encT + (size_t)B*DE*TE;              // 2 MB

  const bool use_dwt = ws_size >= (size_t)(B*DE*TE + B*TD*DE)*sizeof(float);

  hipLaunchKernelGGL(prep_kernel, dim3(use_dwt ? 1536 : 1024), dim3(256), 0,
                     stream, enc, Wenc, dec, Wdec, encT, decT);
  if (use_dwt){
    hipLaunchKernelGGL((attn_kernel<true>), dim3(512), dim3(512), 0, stream,
                       enc, dec, Wdec, v, encT, decT, outCtx, outW);
  } else {
    hipLaunchKernelGGL((attn_kernel<false>), dim3(512), dim3(512), 0, stream,
                       enc, dec, Wdec, v, encT, decT, outCtx, outW);
  }
}

// Round 6
// 78.675 us; speedup vs baseline: 1.9157x; 1.9157x over previous
//
#include <hip/hip_runtime.h>

// ContextVector additive-attention (Bahdanau) — round 6.
// R6 vs R5:
//  (1) exp-product math: Ea=e^{2a}, Eb=e^{2b}; v*tanh(a+b) = vn*rcp(1+Ea*Eb)
//      (+ const dropped by softmax invariance). Phase-1 = mul+add+rcp+fma.
//  (2) attn grid 512x1024 (8192 waves = machine capacity; R5 grid capped 50%).
//  (3) prep GEMMs: scalar-pipe A loads (wave-uniform rows) + coalesced W loads;
//      enc output transposed via padded LDS tile -> full-line global writes.
//      (R1-R5 prep had 64-transaction uncoalesced A reads.)

constexpr int B  = 8;
constexpr int TE = 512;   // T_enc
constexpr int DE = 256;   // D_enc
constexpr int TD = 256;   // T_dec
constexpr int DD = 512;   // D_dec

constexpr float LOG2E  = 1.4426950408889634f;
constexpr float K2     = 2.8853900817779268f;   // 2*log2(e): exp2(K2*z) = e^{2z}
constexpr float ACLAMP = 20.0f;                 // e^{2*20}=2^57.7; product 2^115 ok

typedef float f2 __attribute__((ext_vector_type(2)));

__device__ __forceinline__ float fexp2(float x){ return __builtin_amdgcn_exp2f(x); }
__device__ __forceinline__ float frcp (float x){ return __builtin_amdgcn_rcpf(x); }
__device__ __forceinline__ f2 pk_add(f2 a, f2 b){ f2 d; asm("v_pk_add_f32 %0, %1, %2":"=v"(d):"v"(a),"v"(b)); return d; }
__device__ __forceinline__ f2 pk_mul(f2 a, f2 b){ f2 d; asm("v_pk_mul_f32 %0, %1, %2":"=v"(d):"v"(a),"v"(b)); return d; }
__device__ __forceinline__ f2 pk_fma(f2 a, f2 b, f2 c){ f2 d; asm("v_pk_fma_f32 %0, %1, %2, %3":"=v"(d):"v"(a),"v"(b),"v"(c)); return d; }

__device__ __forceinline__ float e2z(float z){   // e^{2z}, clamped
  return fexp2(K2 * fminf(fmaxf(z, -ACLAMP), ACLAMP));
}

// Prep: bid<256: encE[b][e][t] = e^{2*(enc@Wenc)} transposed store, 16 t-rows/block
//       bid>=256: decE[b*TD+s][e] = e^{2*(dec@Wdec)} row-major, 8 s-rows/block
// A-row elements are wave-uniform -> scalar loads; W loads lane-coalesced.
__global__ __launch_bounds__(256)
void prep_kernel(const float* __restrict__ enc, const float* __restrict__ Wenc,
                 const float* __restrict__ dec, const float* __restrict__ Wdec,
                 float* __restrict__ encE, float* __restrict__ decE)
{
  __shared__ __align__(16) float LT[16][257];   // enc branch transpose tile
  const int tid = threadIdx.x;
  const int bid = blockIdx.x;
  if (bid < 256){
    const int r0 = bid*16;                 // global row = b*TE + t
    const int b = r0 >> 9, t0 = r0 & (TE-1);
    const int col = tid;
    float acc[16];
    #pragma unroll
    for (int r=0;r<16;r++) acc[r]=0.f;
    const float* Arow = enc + (size_t)r0*DE;
    const float* wp   = Wenc + col;
    for (int k4=0;k4<DE/4;k4++){
      const float w0 = wp[(size_t)(4*k4  )*DE];   // coalesced over lanes
      const float w1 = wp[(size_t)(4*k4+1)*DE];
      const float w2 = wp[(size_t)(4*k4+2)*DE];
      const float w3 = wp[(size_t)(4*k4+3)*DE];
      #pragma unroll
      for (int r=0;r<16;r++){
        const float4 av = *(const float4*)(Arow + (size_t)r*DE + 4*k4); // uniform -> s_load
        acc[r] += av.x*w0 + av.y*w1 + av.z*w2 + av.w*w3;
      }
    }
    #pragma unroll
    for (int r=0;r<16;r++) LT[r][col] = e2z(acc[r]);
    __syncthreads();
    // store: wave writes 16 e-rows x 16 t = full 64B lines
    const int wv = tid>>6, lane = tid&63, le = lane>>2, jj = lane&3;
    #pragma unroll
    for (int p=0;p<4;p++){
      const int e = p*64 + wv*16 + le;
      float4 val;
      val.x = LT[4*jj+0][e]; val.y = LT[4*jj+1][e];
      val.z = LT[4*jj+2][e]; val.w = LT[4*jj+3][e];
      *(float4*)(encE + (size_t)(b*DE + e)*TE + t0 + 4*jj) = val;
    }
  } else {
    const int r0 = (bid-256)*8;            // global row = b*TD + s
    const int col = tid;
    float acc[8];
    #pragma unroll
    for (int r=0;r<8;r++) acc[r]=0.f;
    const float* Arow = dec + (size_t)r0*DD;
    const float* wp   = Wdec + col;
    for (int k4=0;k4<DD/4;k4++){
      const float w0 = wp[(size_t)(4*k4  )*DE];
      const float w1 = wp[(size_t)(4*k4+1)*DE];
      const float w2 = wp[(size_t)(4*k4+2)*DE];
      const float w3 = wp[(size_t)(4*k4+3)*DE];
      #pragma unroll
      for (int r=0;r<8;r++){
        const float4 av = *(const float4*)(Arow + (size_t)r*DD + 4*k4); // uniform
        acc[r] += av.x*w0 + av.y*w1 + av.z*w2 + av.w*w3;
      }
    }
    #pragma unroll
    for (int r=0;r<8;r++)
      decE[(size_t)(r0+r)*DE + col] = e2z(acc[r]);   // coalesced
  }
}

// Main: block = (b, 4 decoder steps). 512 blocks x 1024 threads (16 waves).
// phase1: logit'[s][t] = sum_e vn_e * rcp(1 + Ea[e][t]*Eb[s][e])   (log2 domain)
// phase2: weights = 2^logit' / sum (no max-subtract: |logit'| <= 80)
// phase3: context = weights @ enc
template<bool USE_DWT>
__global__ __launch_bounds__(1024, 8)
void attn_kernel(const float* __restrict__ enc, const float* __restrict__ dec,
                 const float* __restrict__ Wdec, const float* __restrict__ v,
                 const float* __restrict__ encE, const float* __restrict__ decE,
                 float* __restrict__ outCtx, float* __restrict__ outW)
{
  __shared__ __align__(16) float ebp[DE*4*2];   // 8 KB {Eb,Eb} pairs per (e,s)
  __shared__ __align__(16) float vnp[DE*2];     // 2 KB {vn,vn} pairs
  __shared__ __align__(16) float part[16*TE];   // 32 KB [g*4+s][t]; multi-use
  __shared__ float wsum[16], rs[4];

  const int tid = threadIdx.x;
  const int bid = ((blockIdx.x & 7) << 6) | (blockIdx.x >> 3);  // XCD-bijective
  const int b  = bid >> 6;
  const int s0 = (bid & 63)*4;

  if (USE_DWT){
    if (tid < DE){
      const float* dp = decE + (size_t)(b*TD + s0)*DE + tid;
      const float g0 = dp[0], g1 = dp[DE], g2 = dp[2*DE], g3 = dp[3*DE];
      float4 q0; q0.x=g0; q0.y=g0; q0.z=g1; q0.w=g1;
      float4 q1; q1.x=g2; q1.y=g2; q1.z=g3; q1.w=g3;
      *(float4*)&ebp[tid*8]   = q0;
      *(float4*)&ebp[tid*8+4] = q1;
      const float vnv = -2.f*LOG2E*v[tid];
      *(f2*)&vnp[tid*2] = f2{vnv, vnv};
    }
    __syncthreads();
  } else {
    {  // stage 4 dec rows into part (2048 floats)
      const float* src = dec + (size_t)(b*TD + s0)*DD;
      part[tid] = src[tid];
      part[tid + 1024] = src[tid + 1024];
    }
    __syncthreads();
    const int s = tid >> 8, e = tid & 255;     // thread = (s, e), 512-MAC dot
    float a = 0.f;
    const float* wp  = Wdec + e;
    const float* dsp = part + s*DD;            // uniform per wave
    #pragma unroll 2
    for (int k4=0;k4<DD/4;k4++){
      const float4 qd = *(const float4*)(dsp + 4*k4);
      a += qd.x*wp[(size_t)(4*k4  )*DE] + qd.y*wp[(size_t)(4*k4+1)*DE]
         + qd.z*wp[(size_t)(4*k4+2)*DE] + qd.w*wp[(size_t)(4*k4+3)*DE];
    }
    const float eb = e2z(a);
    __syncthreads();                           // part re-used below
    *(f2*)&ebp[(e*4 + s)*2] = f2{eb, eb};
    if (s == 0) *(f2*)&vnp[e*2] = f2{-2.f*LOG2E*v[e], -2.f*LOG2E*v[e]};
    __syncthreads();
  }

  // ---- phase 1: thread (g = e-quarter, q = t-pair). 64 e x 4 s x 2 t ----
  {
    const int g = tid >> 8, q = tid & 255;
    f2 acc0 = f2{0.f,0.f}, acc1 = f2{0.f,0.f}, acc2 = f2{0.f,0.f}, acc3 = f2{0.f,0.f};
    const f2 one2 = {1.f, 1.f};
    const float* xp = encE + (size_t)(b*DE + 64*g)*TE + 2*q;
    const float* ep = ebp + 64*g*8;
    const float* np = vnp + 64*g*2;
    #pragma unroll 2
    for (int i=0;i<64;i++){
      const f2 ea = *(const f2*)(xp + (size_t)i*TE);     // coalesced b64
      const float4 e01 = *(const float4*)(ep + i*8);     // uniform b128 {s0s0 s1s1}
      const float4 e23 = *(const float4*)(ep + i*8 + 4); // uniform b128 {s2s2 s3s3}
      const f2 vn2 = *(const f2*)(np + i*2);             // uniform b64
      const f2 p0 = pk_mul(ea, f2{e01.x, e01.y});
      const f2 p1 = pk_mul(ea, f2{e01.z, e01.w});
      const f2 p2 = pk_mul(ea, f2{e23.x, e23.y});
      const f2 p3 = pk_mul(ea, f2{e23.z, e23.w});
      const f2 d0 = pk_add(one2, p0);
      const f2 d1 = pk_add(one2, p1);
      const f2 d2 = pk_add(one2, p2);
      const f2 d3 = pk_add(one2, p3);
      const f2 r0 = {frcp(d0.x), frcp(d0.y)};
      const f2 r1 = {frcp(d1.x), frcp(d1.y)};
      const f2 r2 = {frcp(d2.x), frcp(d2.y)};
      const f2 r3 = {frcp(d3.x), frcp(d3.y)};
      acc0 = pk_fma(vn2, r0, acc0);
      acc1 = pk_fma(vn2, r1, acc1);
      acc2 = pk_fma(vn2, r2, acc2);
      acc3 = pk_fma(vn2, r3, acc3);
    }
    *(f2*)&part[(g*4 + 0)*TE + 2*q] = acc0;
    *(f2*)&part[(g*4 + 1)*TE + 2*q] = acc1;
    *(f2*)&part[(g*4 + 2)*TE + 2*q] = acc2;
    *(f2*)&part[(g*4 + 3)*TE + 2*q] = acc3;
  }
  __syncthreads();

  // ---- phase 2: wave w: s = w>>2, chunk c = w&3 (128 t). no max-subtract ----
  {
    const int w = tid >> 6, lane = tid & 63;
    const int s = w >> 2, c = w & 3;
    const int t0 = c*128 + 2*lane;
    f2 a = f2{0.f,0.f};
    #pragma unroll
    for (int g=0; g<4; g++){
      const f2 p = *(const f2*)&part[(g*4 + s)*TE + t0];
      a.x += p.x; a.y += p.y;
    }
    f2 ex; ex.x = fexp2(a.x); ex.y = fexp2(a.y);
    *(f2*)&part[(0*4 + s)*TE + t0] = ex;       // own slot (read above first)
    float sum = ex.x + ex.y;
    #pragma unroll
    for (int off=32; off>=1; off>>=1) sum += __shfl_xor(sum, off);
    if (lane==0) wsum[w] = sum;
    __syncthreads();
    const float S = wsum[s*4] + wsum[s*4+1] + wsum[s*4+2] + wsum[s*4+3];
    const float r = 1.0f / S;
    f2 wo; wo.x = ex.x*r; wo.y = ex.y*r;
    *(f2*)(outW + (size_t)(b*TD + s0 + s)*TE + t0) = wo;
    if (lane==0 && c==0) rs[s] = r;
  }
  // no barrier needed before phase 3 compute reads (ex rows 0-3 were
  // published before the wsum barrier; partials go to rows 8-15 which all
  // phase-2 reads already consumed before that same barrier)

  // ---- phase 3: context. thread (h = t-quarter, e). 128 t x 4 s ----
  {
    const int h = tid >> 8, e = tid & 255;
    float c0=0.f, c1=0.f, c2=0.f, c3=0.f;
    const float* encB = enc + (size_t)(b*TE + 128*h)*DE + e;
    const int tb = 128*h;
    #pragma unroll 2
    for (int t4=0;t4<32;t4++){
      const float4 q0 = *(const float4*)&part[0*TE + tb + 4*t4];   // uniform b128
      const float4 q1 = *(const float4*)&part[1*TE + tb + 4*t4];
      const float4 q2 = *(const float4*)&part[2*TE + tb + 4*t4];
      const float4 q3 = *(const float4*)&part[3*TE + tb + 4*t4];
      const float f0 = encB[(size_t)(4*t4  )*DE];                  // coalesced
      const float f1 = encB[(size_t)(4*t4+1)*DE];
      const float f2_ = encB[(size_t)(4*t4+2)*DE];
      const float f3 = encB[(size_t)(4*t4+3)*DE];
      c0 += q0.x*f0+q0.y*f1+q0.z*f2_+q0.w*f3;
      c1 += q1.x*f0+q1.y*f1+q1.z*f2_+q1.w*f3;
      c2 += q2.x*f0+q2.y*f1+q2.z*f2_+q2.w*f3;
      c3 += q3.x*f0+q3.y*f1+q3.z*f2_+q3.w*f3;
    }
    float* partc = part + 8*TE;    // rows 8-15: [h*4+s][e]
    partc[(h*4+0)*DE + e] = c0;
    partc[(h*4+1)*DE + e] = c1;
    partc[(h*4+2)*DE + e] = c2;
    partc[(h*4+3)*DE + e] = c3;
  }
  __syncthreads();
  if (tid < DE){
    const float* partc = part + 8*TE;
    #pragma unroll
    for (int s=0;s<4;s++){
      const float val = (partc[(0*4+s)*DE + tid] + partc[(1*4+s)*DE + tid]
                       + partc[(2*4+s)*DE + tid] + partc[(3*4+s)*DE + tid]) * rs[s];
      outCtx[(size_t)(b*TD + s0 + s)*DE + tid] = val;
    }
  }
}

extern "C" void kernel_launch(void* const* d_in, const int* in_sizes, int n_in,
                              void* d_out, int out_size, void* d_ws, size_t ws_size,
                              hipStream_t stream)
{
  const float* enc  = (const float*)d_in[0];
  const float* dec  = (const float*)d_in[1];
  const float* Wenc = (const float*)d_in[2];
  const float* Wdec = (const float*)d_in[3];
  const float* v    = (const float*)d_in[4];
  float* outCtx = (float*)d_out;                       // (8,256,256)
  float* outW   = outCtx + (size_t)B*TD*DE;            // (8,256,512)
  float* encE   = (float*)d_ws;                        // 4 MB
  float* decE   = encE + (size_t)B*DE*TE;              // 2 MB

  const bool use_dwt = ws_size >= (size_t)(B*DE*TE + B*TD*DE)*sizeof(float);

  hipLaunchKernelGGL(prep_kernel, dim3(512), dim3(256), 0, stream,
                     enc, Wenc, dec, Wdec, encE, decE);
  if (use_dwt){
    hipLaunchKernelGGL((attn_kernel<true>), dim3(512), dim3(1024), 0, stream,
                       enc, dec, Wdec, v, encE, decE, outCtx, outW);
  } else {
    hipLaunchKernelGGL((attn_kernel<false>), dim3(512), dim3(1024), 0, stream,
                       enc, dec, Wdec, v, encE, decE, outCtx, outW);
  }
}